// Round 15
// baseline (1037.731 us; speedup 1.0000x reference)
//
#include <hip/hip_runtime.h>
#include <hip/hip_bf16.h>

namespace {
constexpr int kNC = 50000;
constexpr int kNT = 30000;
constexpr int kND = 20000;
constexpr int kN  = 100000;   // total nodes
constexpr int kR  = 4;        // relations
constexpr int kER = 400000;   // edges per relation
constexpr int kE  = kR * kER; // 1.6M edges
constexpr int kH  = 256;      // hidden dim
constexpr int kB  = kR * kN;  // CSR buckets (relation-major)

constexpr int padM(int m) { return (m + 127) / 128 * 128; }
}

typedef __attribute__((ext_vector_type(8))) short short8;
typedef __attribute__((ext_vector_type(4))) float f32x4;
typedef __attribute__((ext_vector_type(4))) unsigned short us4;

__device__ __forceinline__ unsigned short f2bf(float x) {
    unsigned u = __builtin_bit_cast(unsigned, x);
    u += 0x7FFF + ((u >> 16) & 1);      // RNE
    return (unsigned short)(u >> 16);
}
__device__ __forceinline__ float bf2f(unsigned short u) {
    unsigned v = ((unsigned)u) << 16;
    return __builtin_bit_cast(float, v);
}
__device__ __forceinline__ float bf2f_s(short u) {
    unsigned v = ((unsigned)(unsigned short)u) << 16;
    return __builtin_bit_cast(float, v);
}

__device__ __forceinline__ void gld16(const void* src, void* lds) {
    __builtin_amdgcn_global_load_lds(
        (const __attribute__((address_space(1))) void*)src,
        (__attribute__((address_space(3))) void*)lds, 16, 0, 0);
}

__device__ __forceinline__ void nt_store_f(float* p, float v) {
    __builtin_nontemporal_store(v, p);
}

// ------------------------------------------------------------------
// bf16 MFMA GEMM (projections + final):
// C[M,256] = A[M,K](bf16) @ Bt[256,K]^T(bf16) + bias
// ------------------------------------------------------------------
__global__ __launch_bounds__(256)
void gemm_mfma(const unsigned short* __restrict__ A, int lda,
               const unsigned short* __restrict__ Bt, int ldb,
               const float* __restrict__ bias,
               float* __restrict__ Cf, unsigned short* __restrict__ Cb,
               int M, int K, int accumulate)
{
    __shared__ __attribute__((aligned(16))) unsigned short As[128 * 32];
    __shared__ __attribute__((aligned(16))) unsigned short Bs[128 * 32];
    const int tid  = threadIdx.x;
    const int lane = tid & 63;
    const int wid  = tid >> 6;
    const int wm   = wid >> 1;
    const int wn   = wid & 1;
    const int row0 = blockIdx.y * 128;
    const int col0 = blockIdx.x * 128;

    const int cr = lane >> 2;
    const int cs = lane & 3;

    const f32x4 z4 = {0.f, 0.f, 0.f, 0.f};
    f32x4 acc[4][4];
    #pragma unroll
    for (int m = 0; m < 4; ++m)
        #pragma unroll
        for (int n = 0; n < 4; ++n) acc[m][n] = z4;

    const int fr = lane & 15;
    const int kb = lane >> 4;

    for (int k0 = 0; k0 < K; k0 += 32) {
        #pragma unroll
        for (int j = 0; j < 2; ++j) {
            const int chunk = wid * 2 + j;
            const int r  = chunk * 16 + cr;
            const int sg = cs ^ ((r >> 1) & 3);
            gld16(A  + (size_t)(row0 + r) * lda + k0 + sg * 8, As + chunk * 512);
            gld16(Bt + (size_t)(col0 + r) * ldb + k0 + sg * 8, Bs + chunk * 512);
        }
        __syncthreads();
        short8 a[4], b[4];
        #pragma unroll
        for (int m = 0; m < 4; ++m) {
            const int am = wm * 64 + m * 16 + fr;
            const int s  = kb ^ ((am >> 1) & 3);
            a[m] = *(const short8*)(As + am * 32 + s * 8);
        }
        #pragma unroll
        for (int n = 0; n < 4; ++n) {
            const int bn = wn * 64 + n * 16 + fr;
            const int s  = kb ^ ((bn >> 1) & 3);
            b[n] = *(const short8*)(Bs + bn * 32 + s * 8);
        }
        #pragma unroll
        for (int m = 0; m < 4; ++m)
            #pragma unroll
            for (int n = 0; n < 4; ++n)
                acc[m][n] = __builtin_amdgcn_mfma_f32_16x16x32_bf16(
                    a[m], b[n], acc[m][n], 0, 0, 0);
        __syncthreads();
    }

    const int fq = lane >> 4;
    #pragma unroll
    for (int m = 0; m < 4; ++m) {
        #pragma unroll
        for (int n = 0; n < 4; ++n) {
            const int col  = col0 + wn * 64 + n * 16 + fr;
            const int rowb = row0 + wm * 64 + m * 16 + fq * 4;
            const float bv = bias ? bias[col] : 0.0f;
            #pragma unroll
            for (int i = 0; i < 4; ++i) {
                const int row = rowb + i;
                if (row >= M) continue;
                const float v = acc[m][n][i] + bv;
                const size_t idx = (size_t)row * kH + col;
                if (Cb) Cb[idx] = f2bf(v);
                else if (accumulate) Cf[idx] += v;
                else nt_store_f(&Cf[idx], v);
            }
        }
    }
}

// ------------------------------------------------------------------
// Fused RGCN layer v15: producer/consumer, 768 threads = 12 waves.
// Waves 0-7 = producers: gather into double-buffered A_seg; each wave
// owns 4 rows/phase (4x16-lane groups, 1 row each, unroll-2 — R8's
// proven gather). Waves 8-11 = consumers: R8's MFMA shape (64-col
// slice, acc[2][4]) + LN epilogue. 2 blocks/CU (thread cap) ->
// 16 DEDICATED gather waves/CU (R8 count, 100% duty) + 8 MFMA waves.
// B fragments from global in fragment-major W2 (coalesced 1KB, L2-hot).
// ------------------------------------------------------------------
__global__ __launch_bounds__(768, 4)
void rgcn_fused(const unsigned short* __restrict__ h_cur,
                const int* __restrict__ off, const int* __restrict__ esort,
                const unsigned short* __restrict__ W2,   // [5][8][256][4][8]
                const float* __restrict__ bias, const float* __restrict__ g,
                const float* __restrict__ b,
                unsigned short* __restrict__ h_nxt, int useResid)
{
    __shared__ __attribute__((aligned(16))) unsigned short A_seg[2][32 * 256]; // 32 KB
    __shared__ float red[2][4][32];                                             // 1 KB

    const int tid  = threadIdx.x;
    const int lane = tid & 63;
    const int wid  = tid >> 6;       // 0..11
    const bool producer = wid < 8;
    const int pw   = wid;            // producer wave 0..7
    const int cw   = wid - 8;        // consumer wave 0..3 (col quarter)
    const int row0 = blockIdx.x * 32;
    const int fr   = lane & 15;
    const int kb   = lane >> 4;
    const int eg   = lane >> 4;      // row-slot group 0..3
    const int sl   = lane & 15;      // 32B slice within row

    const f32x4 z4 = {0.f, 0.f, 0.f, 0.f};
    f32x4 acc[2][4];
    #pragma unroll
    for (int m = 0; m < 2; ++m)
        #pragma unroll
        for (int n = 0; n < 4; ++n) acc[m][n] = z4;

    // ---- producer fill: q<4 gather relation q; q==4 root copy
    auto fill = [&](int q, int buf) {
        char* const aBase = reinterpret_cast<char*>(A_seg[buf]);
        if (q < 4) {
            int offv = 0;
            if (lane < 5) offv = off[(size_t)q * kN + row0 + pw * 4 + lane];
            const int wrow = pw * 4 + eg;
            const int t0 = __shfl(offv, eg);
            const int t1 = __shfl(offv, eg + 1);
            float a[16];
            #pragma unroll
            for (int i = 0; i < 16; ++i) a[i] = 0.f;
            int t = t0;
            for (; t + 2 <= t1; t += 2) {
                const int s0 = esort[t];
                const int s1 = esort[t + 1];
                const short8 v0a = *reinterpret_cast<const short8*>(
                    h_cur + (size_t)s0 * kH + sl * 16);
                const short8 v0b = *reinterpret_cast<const short8*>(
                    h_cur + (size_t)s0 * kH + sl * 16 + 8);
                const short8 v1a = *reinterpret_cast<const short8*>(
                    h_cur + (size_t)s1 * kH + sl * 16);
                const short8 v1b = *reinterpret_cast<const short8*>(
                    h_cur + (size_t)s1 * kH + sl * 16 + 8);
                #pragma unroll
                for (int i = 0; i < 8; ++i) {
                    a[i]     += bf2f_s(v0a[i]) + bf2f_s(v1a[i]);
                    a[8 + i] += bf2f_s(v0b[i]) + bf2f_s(v1b[i]);
                }
            }
            if (t < t1) {
                const int s0 = esort[t];
                const short8 v0a = *reinterpret_cast<const short8*>(
                    h_cur + (size_t)s0 * kH + sl * 16);
                const short8 v0b = *reinterpret_cast<const short8*>(
                    h_cur + (size_t)s0 * kH + sl * 16 + 8);
                #pragma unroll
                for (int i = 0; i < 8; ++i) {
                    a[i]     += bf2f_s(v0a[i]);
                    a[8 + i] += bf2f_s(v0b[i]);
                }
            }
            short8 w0, w1;
            #pragma unroll
            for (int i = 0; i < 8; ++i) {
                w0[i] = (short)f2bf(a[i]);
                w1[i] = (short)f2bf(a[8 + i]);
            }
            const int byte0 = (wrow * 512 + sl * 32) ^ ((wrow & 7) << 4);
            *reinterpret_cast<short8*>(aBase + byte0) = w0;
            *reinterpret_cast<short8*>(aBase + (byte0 ^ 16)) = w1;
        } else {
            // root: copy own h-tile (gld16, swizzle via inverse source addr)
            #pragma unroll
            for (int i = 0; i < 2; ++i) {
                const int base = pw * 2048 + i * 1024;
                const int o = base + lane * 16;
                const int row = o >> 9;
                const int offr = (o & 511) ^ ((row & 7) << 4);
                gld16(h_cur + (size_t)(row0 + row) * kH + (offr >> 1), aBase + base);
            }
        }
    };

    if (producer) fill(0, 0);
    __syncthreads();     // A(0) ready (drains producer vmcnt/LDS writes)

    for (int p = 0; p < 5; ++p) {
        if (producer) {
            if (p < 4) fill(p + 1, (p + 1) & 1);
        } else {
            char* const aBase = reinterpret_cast<char*>(A_seg[p & 1]);
            const unsigned short* Wp = W2 + (size_t)p * 8 * 8192;
            #pragma unroll
            for (int ks = 0; ks < 8; ++ks) {
                const unsigned short* Wks = Wp + ks * 8192;
                const int kByte = ks * 64 + kb * 16;
                short8 a[2], bf[4];
                #pragma unroll
                for (int m = 0; m < 2; ++m) {
                    const int am = m * 16 + fr;
                    const int byte = (am * 512 + kByte) ^ ((am & 7) << 4);
                    a[m] = *reinterpret_cast<const short8*>(aBase + byte);
                }
                #pragma unroll
                for (int n = 0; n < 4; ++n) {
                    const int cn = cw * 64 + n * 16 + fr;
                    bf[n] = *reinterpret_cast<const short8*>(Wks + cn * 32 + kb * 8);
                }
                #pragma unroll
                for (int m = 0; m < 2; ++m)
                    #pragma unroll
                    for (int n = 0; n < 4; ++n)
                        acc[m][n] = __builtin_amdgcn_mfma_f32_16x16x32_bf16(
                            a[m], bf[n], acc[m][n], 0, 0, 0);
            }
        }
        __syncthreads();   // A(p+1) ready; buf[p&1] free for reuse
    }

    // ---- epilogue (consumers): bias + residual + LayerNorm -> h_nxt
    const int fq = lane >> 4;
    if (!producer) {
        #pragma unroll
        for (int m = 0; m < 2; ++m) {
            #pragma unroll
            for (int i = 0; i < 4; ++i) {
                const int rowloc = m * 16 + fq * 4 + i;
                const int row = row0 + rowloc;
                float s = 0.f, q = 0.f;
                #pragma unroll
                for (int n = 0; n < 4; ++n) {
                    const int col = cw * 64 + n * 16 + fr;
                    float v = acc[m][n][i] + bias[col];
                    if (useResid) v += bf2f(h_cur[(size_t)row * kH + col]);
                    acc[m][n][i] = v;
                    s += v;
                    q += v * v;
                }
                #pragma unroll
                for (int w = 1; w <= 8; w <<= 1) {
                    s += __shfl_xor(s, w);
                    q += __shfl_xor(q, w);
                }
                if (fr == 0) { red[0][cw][rowloc] = s; red[1][cw][rowloc] = q; }
            }
        }
    }
    __syncthreads();
    if (!producer) {
        #pragma unroll
        for (int m = 0; m < 2; ++m) {
            #pragma unroll
            for (int i = 0; i < 4; ++i) {
                const int rowloc = m * 16 + fq * 4 + i;
                const int row = row0 + rowloc;
                const float s  = red[0][0][rowloc] + red[0][1][rowloc]
                               + red[0][2][rowloc] + red[0][3][rowloc];
                const float qq = red[1][0][rowloc] + red[1][1][rowloc]
                               + red[1][2][rowloc] + red[1][3][rowloc];
                const float mu = s * (1.0f / kH);
                const float var = qq * (1.0f / kH) - mu * mu;
                const float rstd = rsqrtf(var + 1e-5f);
                #pragma unroll
                for (int n = 0; n < 4; ++n) {
                    const int col = cw * 64 + n * 16 + fr;
                    const float o = (acc[m][n][i] - mu) * rstd * g[col] + b[col];
                    h_nxt[(size_t)row * kH + col] = f2bf(o);
                }
            }
        }
    }
}

// ---------------- dtype prep ----------------

__global__ __launch_bounds__(256)
void conv_bf16(const float* __restrict__ in, unsigned short* __restrict__ out, int n)
{
    int i = (blockIdx.x * 256 + threadIdx.x) * 4;
    if (i >= n) return;
    f32x4 v = *reinterpret_cast<const f32x4*>(in + i);
    us4 o = { f2bf(v.x), f2bf(v.y), f2bf(v.z), f2bf(v.w) };
    *reinterpret_cast<us4*>(out + i) = o;
}

// W [K][256] f32 -> Wt [256][K] bf16
__global__ __launch_bounds__(256)
void wT_bf16(const float* __restrict__ W, unsigned short* __restrict__ Wt, int K)
{
    int t = blockIdx.x * 256 + threadIdx.x;
    if (t >= 256 * K) return;
    int c = t / K, k = t % K;
    Wt[t] = f2bf(W[(size_t)k * 256 + c]);
}

// [w(4x256x256); root(256x256)] -> W2 [5][8][256 col][4 kb][8 e] bf16
__global__ __launch_bounds__(256)
void wstack2_bf16(const float* __restrict__ w, const float* __restrict__ root,
                  unsigned short* __restrict__ W2)
{
    int t = blockIdx.x * 256 + threadIdx.x;
    if (t >= 5 * 8 * 256 * 32) return;
    const int e   = t & 7;
    const int kb  = (t >> 3) & 3;
    const int col = (t >> 5) & 255;
    const int ks  = (t >> 13) & 7;
    const int p   = t >> 16;
    const int k   = p * 256 + ks * 32 + kb * 8 + e;
    const float v = (k < 1024) ? w[(size_t)k * 256 + col]
                               : root[(size_t)(k - 1024) * 256 + col];
    W2[t] = f2bf(v);
}

// ---------------- CSR build ----------------

__global__ __launch_bounds__(256)
void count_deg(const int* __restrict__ dst, int* __restrict__ deg, int nE)
{
    int e = blockIdx.x * 256 + threadIdx.x;
    if (e >= nE) return;
    int r = e / kER;
    atomicAdd(&deg[r * kN + dst[e]], 1);
}

__global__ __launch_bounds__(256)
void chunk_reduce(const int* __restrict__ deg, int* __restrict__ chunkSum, int B)
{
    __shared__ int sm[256];
    int s = 0;
    #pragma unroll
    for (int j = 0; j < 4; ++j) {
        int idx = blockIdx.x * 1024 + j * 256 + threadIdx.x;
        if (idx < B) s += deg[idx];
    }
    sm[threadIdx.x] = s;
    __syncthreads();
    for (int o = 128; o >= 1; o >>= 1) {
        if (threadIdx.x < o) sm[threadIdx.x] += sm[threadIdx.x + o];
        __syncthreads();
    }
    if (threadIdx.x == 0) chunkSum[blockIdx.x] = sm[0];
}

__global__ __launch_bounds__(64)
void scan_chunks(const int* __restrict__ chunkSum, int* __restrict__ chunkBase, int n)
{
    int lane = threadIdx.x;
    int base = 0;
    for (int i0 = 0; i0 < n; i0 += 64) {
        int i = i0 + lane;
        int orig = (i < n) ? chunkSum[i] : 0;
        int v = orig;
        #pragma unroll
        for (int o = 1; o < 64; o <<= 1) {
            int t = __shfl_up(v, o);
            if (lane >= o) v += t;
        }
        if (i < n) chunkBase[i] = base + v - orig;
        base += __shfl(v, 63);
    }
}

__global__ __launch_bounds__(256)
void scan_within(const int* __restrict__ deg, const int* __restrict__ chunkBase,
                 int* __restrict__ off, int B)
{
    __shared__ int ts[256];
    const int i0 = blockIdx.x * 1024;
    int v[4];
    int s = 0;
    #pragma unroll
    for (int j = 0; j < 4; ++j) {
        int idx = i0 + threadIdx.x * 4 + j;
        v[j] = (idx < B) ? deg[idx] : 0;
        s += v[j];
    }
    ts[threadIdx.x] = s;
    __syncthreads();
    for (int o = 1; o < 256; o <<= 1) {
        int u = (threadIdx.x >= o) ? ts[threadIdx.x - o] : 0;
        __syncthreads();
        ts[threadIdx.x] += u;
        __syncthreads();
    }
    int run = chunkBase[blockIdx.x] + ts[threadIdx.x] - s;
    #pragma unroll
    for (int j = 0; j < 4; ++j) {
        int idx = i0 + threadIdx.x * 4 + j;
        if (idx <= B) off[idx] = run;
        run += v[j];
    }
}

__global__ __launch_bounds__(256)
void fill_csr(const int* __restrict__ src, const int* __restrict__ dst,
              int* __restrict__ cursor, int* __restrict__ esort, int nE)
{
    int e = blockIdx.x * 256 + threadIdx.x;
    if (e >= nE) return;
    int r = e / kER;
    int pos = atomicAdd(&cursor[r * kN + dst[e]], 1);
    esort[pos] = src[e];
}

// ------------------------------------------------------------------

extern "C" void kernel_launch(void* const* d_in, const int* in_sizes, int n_in,
                              void* d_out, int out_size, void* d_ws, size_t ws_size,
                              hipStream_t stream)
{
    const float* x_c  = (const float*)d_in[0];
    const float* x_t  = (const float*)d_in[1];
    const float* x_d  = (const float*)d_in[2];
    const int*   ei   = (const int*)d_in[3];
    const float* Wp_c = (const float*)d_in[4];
    const float* bp_c = (const float*)d_in[5];
    const float* Wp_t = (const float*)d_in[6];
    const float* bp_t = (const float*)d_in[7];
    const float* Wp_d = (const float*)d_in[8];
    const float* bp_d = (const float*)d_in[9];
    const float* rgcn_w    = (const float*)d_in[10];
    const float* rgcn_root = (const float*)d_in[11];
    const float* rgcn_b    = (const float*)d_in[12];
    const float* ln_g = (const float*)d_in[13];
    const float* ln_b = (const float*)d_in[14];
    const float* Wo   = (const float*)d_in[15];
    const float* bo   = (const float*)d_in[16];

    const int* src_base = ei;
    const int* dst_base = ei + (size_t)kE;

    const int nChunks = (kB + 1023) / 1024;
    const int pN  = padM(kN);    // 100096
    const int pNC = padM(kNC);
    const int pNT = padM(kNT);
    const int pND = padM(kND);

    // ---- workspace carve
    char* p = (char*)d_ws;
    unsigned short* hA = (unsigned short*)p;  p += (size_t)pN * kH * 2;
    unsigned short* hB = (unsigned short*)p;  p += (size_t)pN * kH * 2;
    unsigned short* xbf_c = (unsigned short*)p;  p += (size_t)pNC * 256 * 2;
    unsigned short* xbf_t = (unsigned short*)p;  p += (size_t)pNT * 512 * 2;
    unsigned short* xbf_d = (unsigned short*)p;  p += (size_t)pND * 128 * 2;
    unsigned short* Wt_c = (unsigned short*)p;          // [256][256]
    unsigned short* Wt_t = Wt_c + 256 * 256;            // [256][512]
    unsigned short* Wt_d = Wt_t + 256 * 512;            // [256][128]
    unsigned short* W2   = Wt_d + 256 * 128;            // [2][5*8*256*32]
    unsigned short* Wt_o = W2 + 2 * 5 * 8 * 256 * 32;   // [256][256]
    p = (char*)(Wt_o + 256 * 256);

    int* deg    = (int*)p;
    int* off    = deg + kB;
    int* esort  = off + (kB + 1);
    int* chunkS = esort + kE;
    int* chunkB = chunkS + 1024;

    float* outf = (float*)d_out;   // final y (f32)

    const dim3 blk(256);

    // ---- CSR build
    hipMemsetAsync(deg, 0, (size_t)kB * sizeof(int), stream);
    count_deg<<<dim3((kE + 255) / 256), blk, 0, stream>>>(dst_base, deg, kE);
    chunk_reduce<<<dim3(nChunks), blk, 0, stream>>>(deg, chunkS, kB);
    scan_chunks<<<dim3(1), dim3(64), 0, stream>>>(chunkS, chunkB, nChunks);
    scan_within<<<dim3(nChunks), blk, 0, stream>>>(deg, chunkB, off, kB);
    hipMemcpyAsync(deg, off, (size_t)kB * sizeof(int), hipMemcpyDeviceToDevice, stream);
    fill_csr<<<dim3((kE + 255) / 256), blk, 0, stream>>>(src_base, dst_base, deg, esort, kE);

    // ---- dtype prep
    conv_bf16<<<dim3((kNC * 256 / 4 + 255) / 256), blk, 0, stream>>>(x_c, xbf_c, kNC * 256);
    conv_bf16<<<dim3((kNT * 512 / 4 + 255) / 256), blk, 0, stream>>>(x_t, xbf_t, kNT * 512);
    conv_bf16<<<dim3((kND * 128 / 4 + 255) / 256), blk, 0, stream>>>(x_d, xbf_d, kND * 128);
    wT_bf16<<<dim3((256 * 256 + 255) / 256), blk, 0, stream>>>(Wp_c, Wt_c, 256);
    wT_bf16<<<dim3((256 * 512 + 255) / 256), blk, 0, stream>>>(Wp_t, Wt_t, 512);
    wT_bf16<<<dim3((256 * 128 + 255) / 256), blk, 0, stream>>>(Wp_d, Wt_d, 128);
    wT_bf16<<<dim3((256 * 256 + 255) / 256), blk, 0, stream>>>(Wo, Wt_o, 256);
    for (int l = 0; l < 2; ++l)
        wstack2_bf16<<<dim3(5 * 8 * 256 * 32 / 256), blk, 0, stream>>>(
            rgcn_w + (size_t)l * kR * kH * kH, rgcn_root + (size_t)l * kH * kH,
            W2 + (size_t)l * 5 * 8 * 256 * 32);

    // ---- projections -> hA
    gemm_mfma<<<dim3(2, pNC / 128), blk, 0, stream>>>(
        xbf_c, 256, Wt_c, 256, bp_c, nullptr, hA, kNC, 256, 0);
    gemm_mfma<<<dim3(2, pNT / 128), blk, 0, stream>>>(
        xbf_t, 512, Wt_t, 512, bp_t, nullptr, hA + (size_t)kNC * kH, kNT, 512, 0);
    gemm_mfma<<<dim3(2, pND / 128), blk, 0, stream>>>(
        xbf_d, 128, Wt_d, 128, bp_d, nullptr, hA + (size_t)(kNC + kNT) * kH, kND, 128, 0);

    // ---- fused RGCN layers (h double-buffered: hA -> hB -> hA)
    const dim3 fusedGrid(kN / 32);     // 3125
    const dim3 fusedBlk(768);
    rgcn_fused<<<fusedGrid, fusedBlk, 0, stream>>>(
        hA, off, esort, W2, rgcn_b, ln_g, ln_b, hB, 0);
    rgcn_fused<<<fusedGrid, fusedBlk, 0, stream>>>(
        hB, off, esort, W2 + (size_t)5 * 8 * 256 * 32,
        rgcn_b + kH, ln_g + kH, ln_b + kH, hA, 1);

    // ---- final: y = h @ Wo + bo -> d_out (f32)
    gemm_mfma<<<dim3(2, pN / 128), blk, 0, stream>>>(
        hA, 256, Wt_o, 256, bo, outf, nullptr, kN, 256, 0);
}

// Round 16
// 827.115 us; speedup vs baseline: 1.2546x; 1.2546x over previous
//
#include <hip/hip_runtime.h>
#include <hip/hip_bf16.h>

namespace {
constexpr int kNC = 50000;
constexpr int kNT = 30000;
constexpr int kND = 20000;
constexpr int kN  = 100000;   // total nodes
constexpr int kR  = 4;        // relations
constexpr int kER = 400000;   // edges per relation
constexpr int kE  = kR * kER; // 1.6M edges
constexpr int kH  = 256;      // hidden dim
constexpr int kB  = kR * kN;  // CSR buckets (relation-major)

constexpr int padM(int m) { return (m + 127) / 128 * 128; }
}

typedef __attribute__((ext_vector_type(8))) short short8;
typedef __attribute__((ext_vector_type(4))) float f32x4;
typedef __attribute__((ext_vector_type(4))) unsigned short us4;

__device__ __forceinline__ unsigned short f2bf(float x) {
    unsigned u = __builtin_bit_cast(unsigned, x);
    u += 0x7FFF + ((u >> 16) & 1);      // RNE
    return (unsigned short)(u >> 16);
}
__device__ __forceinline__ float bf2f(unsigned short u) {
    unsigned v = ((unsigned)u) << 16;
    return __builtin_bit_cast(float, v);
}
__device__ __forceinline__ float bf2f_s(short u) {
    unsigned v = ((unsigned)(unsigned short)u) << 16;
    return __builtin_bit_cast(float, v);
}

__device__ __forceinline__ void gld16(const void* src, void* lds) {
    __builtin_amdgcn_global_load_lds(
        (const __attribute__((address_space(1))) void*)src,
        (__attribute__((address_space(3))) void*)lds, 16, 0, 0);
}

__device__ __forceinline__ void nt_store_f(float* p, float v) {
    __builtin_nontemporal_store(v, p);
}

// ------------------------------------------------------------------
// bf16 MFMA GEMM (final): C[M,256] = A[M,K](bf16) @ Bt[256,K]^T + bias
// ------------------------------------------------------------------
__global__ __launch_bounds__(256)
void gemm_mfma(const unsigned short* __restrict__ A, int lda,
               const unsigned short* __restrict__ Bt, int ldb,
               const float* __restrict__ bias,
               float* __restrict__ Cf, unsigned short* __restrict__ Cb,
               int M, int K, int accumulate)
{
    __shared__ __attribute__((aligned(16))) unsigned short As[128 * 32];
    __shared__ __attribute__((aligned(16))) unsigned short Bs[128 * 32];
    const int tid  = threadIdx.x;
    const int lane = tid & 63;
    const int wid  = tid >> 6;
    const int wm   = wid >> 1;
    const int wn   = wid & 1;
    const int row0 = blockIdx.y * 128;
    const int col0 = blockIdx.x * 128;

    const int cr = lane >> 2;
    const int cs = lane & 3;

    const f32x4 z4 = {0.f, 0.f, 0.f, 0.f};
    f32x4 acc[4][4];
    #pragma unroll
    for (int m = 0; m < 4; ++m)
        #pragma unroll
        for (int n = 0; n < 4; ++n) acc[m][n] = z4;

    const int fr = lane & 15;
    const int kb = lane >> 4;

    for (int k0 = 0; k0 < K; k0 += 32) {
        #pragma unroll
        for (int j = 0; j < 2; ++j) {
            const int chunk = wid * 2 + j;
            const int r  = chunk * 16 + cr;
            const int sg = cs ^ ((r >> 1) & 3);
            gld16(A  + (size_t)(row0 + r) * lda + k0 + sg * 8, As + chunk * 512);
            gld16(Bt + (size_t)(col0 + r) * ldb + k0 + sg * 8, Bs + chunk * 512);
        }
        __syncthreads();
        short8 a[4], b[4];
        #pragma unroll
        for (int m = 0; m < 4; ++m) {
            const int am = wm * 64 + m * 16 + fr;
            const int s  = kb ^ ((am >> 1) & 3);
            a[m] = *(const short8*)(As + am * 32 + s * 8);
        }
        #pragma unroll
        for (int n = 0; n < 4; ++n) {
            const int bn = wn * 64 + n * 16 + fr;
            const int s  = kb ^ ((bn >> 1) & 3);
            b[n] = *(const short8*)(Bs + bn * 32 + s * 8);
        }
        #pragma unroll
        for (int m = 0; m < 4; ++m)
            #pragma unroll
            for (int n = 0; n < 4; ++n)
                acc[m][n] = __builtin_amdgcn_mfma_f32_16x16x32_bf16(
                    a[m], b[n], acc[m][n], 0, 0, 0);
        __syncthreads();
    }

    const int fq = lane >> 4;
    #pragma unroll
    for (int m = 0; m < 4; ++m) {
        #pragma unroll
        for (int n = 0; n < 4; ++n) {
            const int col  = col0 + wn * 64 + n * 16 + fr;
            const int rowb = row0 + wm * 64 + m * 16 + fq * 4;
            const float bv = bias ? bias[col] : 0.0f;
            #pragma unroll
            for (int i = 0; i < 4; ++i) {
                const int row = rowb + i;
                if (row >= M) continue;
                const float v = acc[m][n][i] + bv;
                const size_t idx = (size_t)row * kH + col;
                if (Cb) Cb[idx] = f2bf(v);
                else if (accumulate) Cf[idx] += v;
                else nt_store_f(&Cf[idx], v);
            }
        }
    }
}

// ------------------------------------------------------------------
// Projection GEMM with f32 A input (in-register convert to bf16):
// Cb[M,256](bf16) = A[M,K](f32) @ Bt[256,K]^T(bf16) + bias.
// A staged via f32 loads + cvt + ds_write into the SAME swizzled
// LDS layout as gld16 staging; B staged via gld16 (bf16 weights).
// ------------------------------------------------------------------
__global__ __launch_bounds__(256)
void gemm_mfma_f32a(const float* __restrict__ A, int lda,
                    const unsigned short* __restrict__ Bt, int ldb,
                    const float* __restrict__ bias,
                    unsigned short* __restrict__ Cb, int M, int K)
{
    __shared__ __attribute__((aligned(16))) unsigned short As[128 * 32];
    __shared__ __attribute__((aligned(16))) unsigned short Bs[128 * 32];
    const int tid  = threadIdx.x;
    const int lane = tid & 63;
    const int wid  = tid >> 6;
    const int wm   = wid >> 1;
    const int wn   = wid & 1;
    const int row0 = blockIdx.y * 128;
    const int col0 = blockIdx.x * 128;

    const int cr = lane >> 2;
    const int cs = lane & 3;

    const f32x4 z4 = {0.f, 0.f, 0.f, 0.f};
    f32x4 acc[4][4];
    #pragma unroll
    for (int m = 0; m < 4; ++m)
        #pragma unroll
        for (int n = 0; n < 4; ++n) acc[m][n] = z4;

    const int fr = lane & 15;
    const int kb = lane >> 4;

    for (int k0 = 0; k0 < K; k0 += 32) {
        #pragma unroll
        for (int j = 0; j < 2; ++j) {
            const int chunk = wid * 2 + j;
            const int r  = chunk * 16 + cr;
            const int sg = cs ^ ((r >> 1) & 3);
            gld16(Bt + (size_t)(col0 + r) * ldb + k0 + sg * 8, Bs + chunk * 512);
            // A: load 8 f32, convert, ds_write 16B to same slot layout
            const int grow = row0 + r;
            short8 w;
            if (grow < M) {
                const float* ap = A + (size_t)grow * lda + k0 + sg * 8;
                const f32x4 f0 = *reinterpret_cast<const f32x4*>(ap);
                const f32x4 f1 = *reinterpret_cast<const f32x4*>(ap + 4);
                w[0] = (short)f2bf(f0.x); w[1] = (short)f2bf(f0.y);
                w[2] = (short)f2bf(f0.z); w[3] = (short)f2bf(f0.w);
                w[4] = (short)f2bf(f1.x); w[5] = (short)f2bf(f1.y);
                w[6] = (short)f2bf(f1.z); w[7] = (short)f2bf(f1.w);
            } else {
                #pragma unroll
                for (int i = 0; i < 8; ++i) w[i] = 0;
            }
            *reinterpret_cast<short8*>(As + chunk * 512 + lane * 8) = w;
        }
        __syncthreads();
        short8 a[4], b[4];
        #pragma unroll
        for (int m = 0; m < 4; ++m) {
            const int am = wm * 64 + m * 16 + fr;
            const int s  = kb ^ ((am >> 1) & 3);
            a[m] = *(const short8*)(As + am * 32 + s * 8);
        }
        #pragma unroll
        for (int n = 0; n < 4; ++n) {
            const int bn = wn * 64 + n * 16 + fr;
            const int s  = kb ^ ((bn >> 1) & 3);
            b[n] = *(const short8*)(Bs + bn * 32 + s * 8);
        }
        #pragma unroll
        for (int m = 0; m < 4; ++m)
            #pragma unroll
            for (int n = 0; n < 4; ++n)
                acc[m][n] = __builtin_amdgcn_mfma_f32_16x16x32_bf16(
                    a[m], b[n], acc[m][n], 0, 0, 0);
        __syncthreads();
    }

    const int fq = lane >> 4;
    #pragma unroll
    for (int m = 0; m < 4; ++m) {
        #pragma unroll
        for (int n = 0; n < 4; ++n) {
            const int col  = col0 + wn * 64 + n * 16 + fr;
            const int rowb = row0 + wm * 64 + m * 16 + fq * 4;
            const float bv = bias[col];
            #pragma unroll
            for (int i = 0; i < 4; ++i) {
                const int row = rowb + i;
                if (row >= M) continue;
                Cb[(size_t)row * kH + col] = f2bf(acc[m][n][i] + bv);
            }
        }
    }
}

// ------------------------------------------------------------------
// Fused RGCN layer (R8 verbatim — proven best structure):
// per block 32 dst rows x 256 cols, 4 waves, serial phases
// (gather -> barrier -> MFMA) per relation + root; cross-block
// overlap at ~3-4 blocks/CU hides MFMA under other blocks' gathers.
// Gather: 4x16-lane groups, each group owns ONE row (unroll-2).
// B fragments from global in fragment-major W2 (coalesced 1KB, L2-hot).
// ------------------------------------------------------------------
__global__ __launch_bounds__(256, 4)
void rgcn_fused(const unsigned short* __restrict__ h_cur,
                const int* __restrict__ off, const int* __restrict__ esort,
                const unsigned short* __restrict__ W2,   // [5][8][256][4][8]
                const float* __restrict__ bias, const float* __restrict__ g,
                const float* __restrict__ b,
                unsigned short* __restrict__ h_nxt, int useResid)
{
    __shared__ __attribute__((aligned(16))) unsigned short A_seg[32 * 256]; // 16 KB
    __shared__ float red[2][4][32];                                          // 1 KB
    __shared__ float gcol[256], bcol[256], biascol[256];                     // 3 KB

    const int tid  = threadIdx.x;
    const int lane = tid & 63;
    const int wid  = tid >> 6;     // 0..3 == col quarter
    const int row0 = blockIdx.x * 32;
    const int fr   = lane & 15;
    const int kb   = lane >> 4;
    const int eg   = lane >> 4;    // row-slot group 0..3
    const int sl   = lane & 15;    // 32B slice within row

    gcol[tid] = g[tid]; bcol[tid] = b[tid]; biascol[tid] = bias[tid];

    const f32x4 z4 = {0.f, 0.f, 0.f, 0.f};
    f32x4 acc[2][4];
    #pragma unroll
    for (int m = 0; m < 2; ++m)
        #pragma unroll
        for (int n = 0; n < 4; ++n) acc[m][n] = z4;

    char* const aBase = reinterpret_cast<char*>(A_seg);

    for (int p = 0; p < 5; ++p) {
        __syncthreads();    // previous phase's MFMA reads of A_seg done
        if (p < 4) {
            // prefetch CSR offsets for this wave's 8 rows (9 values)
            int offv = 0;
            if (lane < 9) offv = off[(size_t)p * kN + row0 + wid * 8 + lane];
            #pragma unroll
            for (int batch = 0; batch < 2; ++batch) {
                // group eg owns row wid*8 + batch*4 + eg
                const int wrow = wid * 8 + batch * 4 + eg;
                const int t0 = __shfl(offv, batch * 4 + eg);
                const int t1 = __shfl(offv, batch * 4 + eg + 1);
                float a[16];
                #pragma unroll
                for (int i = 0; i < 16; ++i) a[i] = 0.f;
                int t = t0;
                for (; t + 2 <= t1; t += 2) {
                    const int s0 = esort[t];
                    const int s1 = esort[t + 1];
                    const short8 v0a = *reinterpret_cast<const short8*>(
                        h_cur + (size_t)s0 * kH + sl * 16);
                    const short8 v0b = *reinterpret_cast<const short8*>(
                        h_cur + (size_t)s0 * kH + sl * 16 + 8);
                    const short8 v1a = *reinterpret_cast<const short8*>(
                        h_cur + (size_t)s1 * kH + sl * 16);
                    const short8 v1b = *reinterpret_cast<const short8*>(
                        h_cur + (size_t)s1 * kH + sl * 16 + 8);
                    #pragma unroll
                    for (int i = 0; i < 8; ++i) {
                        a[i]     += bf2f_s(v0a[i]) + bf2f_s(v1a[i]);
                        a[8 + i] += bf2f_s(v0b[i]) + bf2f_s(v1b[i]);
                    }
                }
                if (t < t1) {
                    const int s0 = esort[t];
                    const short8 v0a = *reinterpret_cast<const short8*>(
                        h_cur + (size_t)s0 * kH + sl * 16);
                    const short8 v0b = *reinterpret_cast<const short8*>(
                        h_cur + (size_t)s0 * kH + sl * 16 + 8);
                    #pragma unroll
                    for (int i = 0; i < 8; ++i) {
                        a[i]     += bf2f_s(v0a[i]);
                        a[8 + i] += bf2f_s(v0b[i]);
                    }
                }
                short8 w0, w1;
                #pragma unroll
                for (int i = 0; i < 8; ++i) {
                    w0[i] = (short)f2bf(a[i]);
                    w1[i] = (short)f2bf(a[8 + i]);
                }
                const int byte0 = (wrow * 512 + sl * 32) ^ ((wrow & 7) << 4);
                *reinterpret_cast<short8*>(aBase + byte0) = w0;
                *reinterpret_cast<short8*>(aBase + (byte0 ^ 16)) = w1;
            }
        } else {
            // root: copy own h-tile (gld16, swizzle via inverse source addr)
            #pragma unroll
            for (int i = 0; i < 4; ++i) {
                const int base = i * 4096 + wid * 1024;
                const int o = base + lane * 16;
                const int row = o >> 9;
                const int offr = (o & 511) ^ ((row & 7) << 4);
                gld16(h_cur + (size_t)(row0 + row) * kH + (offr >> 1), aBase + base);
            }
        }
        __syncthreads();    // A_seg ready (drains vmcnt for gld16 path)

        const unsigned short* Wp = W2 + (size_t)p * 8 * 8192;
        #pragma unroll
        for (int ks = 0; ks < 8; ++ks) {
            const unsigned short* Wks = Wp + ks * 8192;
            const int kByte = ks * 64 + kb * 16;
            short8 a[2], bf[4];
            #pragma unroll
            for (int m = 0; m < 2; ++m) {
                const int am = m * 16 + fr;
                const int byte = (am * 512 + kByte) ^ ((am & 7) << 4);
                a[m] = *reinterpret_cast<const short8*>(aBase + byte);
            }
            #pragma unroll
            for (int n = 0; n < 4; ++n) {
                const int cn = wid * 64 + n * 16 + fr;
                bf[n] = *reinterpret_cast<const short8*>(Wks + cn * 32 + kb * 8);
            }
            #pragma unroll
            for (int m = 0; m < 2; ++m)
                #pragma unroll
                for (int n = 0; n < 4; ++n)
                    acc[m][n] = __builtin_amdgcn_mfma_f32_16x16x32_bf16(
                        a[m], bf[n], acc[m][n], 0, 0, 0);
        }
    }

    // ---- epilogue: bias + residual + LayerNorm, write h_nxt (bf16)
    const int fq = lane >> 4;
    #pragma unroll
    for (int m = 0; m < 2; ++m) {
        #pragma unroll
        for (int i = 0; i < 4; ++i) {
            const int rowloc = m * 16 + fq * 4 + i;
            const int row = row0 + rowloc;
            float s = 0.f, q = 0.f;
            #pragma unroll
            for (int n = 0; n < 4; ++n) {
                const int col = wid * 64 + n * 16 + fr;
                float v = acc[m][n][i] + biascol[col];
                if (useResid) v += bf2f(h_cur[(size_t)row * kH + col]);
                acc[m][n][i] = v;
                s += v;
                q += v * v;
            }
            #pragma unroll
            for (int w = 1; w <= 8; w <<= 1) {
                s += __shfl_xor(s, w);
                q += __shfl_xor(q, w);
            }
            if (fr == 0) { red[0][wid][rowloc] = s; red[1][wid][rowloc] = q; }
        }
    }
    __syncthreads();
    #pragma unroll
    for (int m = 0; m < 2; ++m) {
        #pragma unroll
        for (int i = 0; i < 4; ++i) {
            const int rowloc = m * 16 + fq * 4 + i;
            const int row = row0 + rowloc;
            const float s  = red[0][0][rowloc] + red[0][1][rowloc]
                           + red[0][2][rowloc] + red[0][3][rowloc];
            const float qq = red[1][0][rowloc] + red[1][1][rowloc]
                           + red[1][2][rowloc] + red[1][3][rowloc];
            const float mu = s * (1.0f / kH);
            const float var = qq * (1.0f / kH) - mu * mu;
            const float rstd = rsqrtf(var + 1e-5f);
            #pragma unroll
            for (int n = 0; n < 4; ++n) {
                const int col = wid * 64 + n * 16 + fr;
                const float o = (acc[m][n][i] - mu) * rstd * gcol[col] + bcol[col];
                h_nxt[(size_t)row * kH + col] = f2bf(o);
            }
        }
    }
}

// ---------------- weight prep ----------------

// W [K][256] f32 -> Wt [256][K] bf16
__global__ __launch_bounds__(256)
void wT_bf16(const float* __restrict__ W, unsigned short* __restrict__ Wt, int K)
{
    int t = blockIdx.x * 256 + threadIdx.x;
    if (t >= 256 * K) return;
    int c = t / K, k = t % K;
    Wt[t] = f2bf(W[(size_t)k * 256 + c]);
}

// [w(4x256x256); root(256x256)] -> W2 [5][8][256 col][4 kb][8 e] bf16
__global__ __launch_bounds__(256)
void wstack2_bf16(const float* __restrict__ w, const float* __restrict__ root,
                  unsigned short* __restrict__ W2)
{
    int t = blockIdx.x * 256 + threadIdx.x;
    if (t >= 5 * 8 * 256 * 32) return;
    const int e   = t & 7;
    const int kb  = (t >> 3) & 3;
    const int col = (t >> 5) & 255;
    const int ks  = (t >> 13) & 7;
    const int p   = t >> 16;
    const int k   = p * 256 + ks * 32 + kb * 8 + e;
    const float v = (k < 1024) ? w[(size_t)k * 256 + col]
                               : root[(size_t)(k - 1024) * 256 + col];
    W2[t] = f2bf(v);
}

// ---------------- CSR build ----------------

__global__ __launch_bounds__(256)
void count_deg(const int* __restrict__ dst, int* __restrict__ deg, int nE)
{
    int e = blockIdx.x * 256 + threadIdx.x;
    if (e >= nE) return;
    int r = e / kER;
    atomicAdd(&deg[r * kN + dst[e]], 1);
}

__global__ __launch_bounds__(256)
void chunk_reduce(const int* __restrict__ deg, int* __restrict__ chunkSum, int B)
{
    __shared__ int sm[256];
    int s = 0;
    #pragma unroll
    for (int j = 0; j < 4; ++j) {
        int idx = blockIdx.x * 1024 + j * 256 + threadIdx.x;
        if (idx < B) s += deg[idx];
    }
    sm[threadIdx.x] = s;
    __syncthreads();
    for (int o = 128; o >= 1; o >>= 1) {
        if (threadIdx.x < o) sm[threadIdx.x] += sm[threadIdx.x + o];
        __syncthreads();
    }
    if (threadIdx.x == 0) chunkSum[blockIdx.x] = sm[0];
}

__global__ __launch_bounds__(64)
void scan_chunks(const int* __restrict__ chunkSum, int* __restrict__ chunkBase, int n)
{
    int lane = threadIdx.x;
    int base = 0;
    for (int i0 = 0; i0 < n; i0 += 64) {
        int i = i0 + lane;
        int orig = (i < n) ? chunkSum[i] : 0;
        int v = orig;
        #pragma unroll
        for (int o = 1; o < 64; o <<= 1) {
            int t = __shfl_up(v, o);
            if (lane >= o) v += t;
        }
        if (i < n) chunkBase[i] = base + v - orig;
        base += __shfl(v, 63);
    }
}

__global__ __launch_bounds__(256)
void scan_within(const int* __restrict__ deg, const int* __restrict__ chunkBase,
                 int* __restrict__ off, int B)
{
    __shared__ int ts[256];
    const int i0 = blockIdx.x * 1024;
    int v[4];
    int s = 0;
    #pragma unroll
    for (int j = 0; j < 4; ++j) {
        int idx = i0 + threadIdx.x * 4 + j;
        v[j] = (idx < B) ? deg[idx] : 0;
        s += v[j];
    }
    ts[threadIdx.x] = s;
    __syncthreads();
    for (int o = 1; o < 256; o <<= 1) {
        int u = (threadIdx.x >= o) ? ts[threadIdx.x - o] : 0;
        __syncthreads();
        ts[threadIdx.x] += u;
        __syncthreads();
    }
    int run = chunkBase[blockIdx.x] + ts[threadIdx.x] - s;
    #pragma unroll
    for (int j = 0; j < 4; ++j) {
        int idx = i0 + threadIdx.x * 4 + j;
        if (idx <= B) off[idx] = run;
        run += v[j];
    }
}

__global__ __launch_bounds__(256)
void fill_csr(const int* __restrict__ src, const int* __restrict__ dst,
              int* __restrict__ cursor, int* __restrict__ esort, int nE)
{
    int e = blockIdx.x * 256 + threadIdx.x;
    if (e >= nE) return;
    int r = e / kER;
    int pos = atomicAdd(&cursor[r * kN + dst[e]], 1);
    esort[pos] = src[e];
}

// ------------------------------------------------------------------

extern "C" void kernel_launch(void* const* d_in, const int* in_sizes, int n_in,
                              void* d_out, int out_size, void* d_ws, size_t ws_size,
                              hipStream_t stream)
{
    const float* x_c  = (const float*)d_in[0];
    const float* x_t  = (const float*)d_in[1];
    const float* x_d  = (const float*)d_in[2];
    const int*   ei   = (const int*)d_in[3];
    const float* Wp_c = (const float*)d_in[4];
    const float* bp_c = (const float*)d_in[5];
    const float* Wp_t = (const float*)d_in[6];
    const float* bp_t = (const float*)d_in[7];
    const float* Wp_d = (const float*)d_in[8];
    const float* bp_d = (const float*)d_in[9];
    const float* rgcn_w    = (const float*)d_in[10];
    const float* rgcn_root = (const float*)d_in[11];
    const float* rgcn_b    = (const float*)d_in[12];
    const float* ln_g = (const float*)d_in[13];
    const float* ln_b = (const float*)d_in[14];
    const float* Wo   = (const float*)d_in[15];
    const float* bo   = (const float*)d_in[16];

    const int* src_base = ei;
    const int* dst_base = ei + (size_t)kE;

    const int nChunks = (kB + 1023) / 1024;
    const int pN  = padM(kN);    // 100096
    const int pNC = padM(kNC);
    const int pNT = padM(kNT);
    const int pND = padM(kND);

    // ---- workspace carve
    char* p = (char*)d_ws;
    unsigned short* hA = (unsigned short*)p;  p += (size_t)pN * kH * 2;
    unsigned short* hB = (unsigned short*)p;  p += (size_t)pN * kH * 2;
    unsigned short* Wt_c = (unsigned short*)p;          // [256][256]
    unsigned short* Wt_t = Wt_c + 256 * 256;            // [256][512]
    unsigned short* Wt_d = Wt_t + 256 * 512;            // [256][128]
    unsigned short* W2   = Wt_d + 256 * 128;            // [2][5*8*256*32]
    unsigned short* Wt_o = W2 + 2 * 5 * 8 * 256 * 32;   // [256][256]
    p = (char*)(Wt_o + 256 * 256);

    int* deg    = (int*)p;
    int* off    = deg + kB;
    int* esort  = off + (kB + 1);
    int* chunkS = esort + kE;
    int* chunkB = chunkS + 1024;

    float* outf = (float*)d_out;   // final y (f32)

    const dim3 blk(256);

    // ---- CSR build
    hipMemsetAsync(deg, 0, (size_t)kB * sizeof(int), stream);
    count_deg<<<dim3((kE + 255) / 256), blk, 0, stream>>>(dst_base, deg, kE);
    chunk_reduce<<<dim3(nChunks), blk, 0, stream>>>(deg, chunkS, kB);
    scan_chunks<<<dim3(1), dim3(64), 0, stream>>>(chunkS, chunkB, nChunks);
    scan_within<<<dim3(nChunks), blk, 0, stream>>>(deg, chunkB, off, kB);
    hipMemcpyAsync(deg, off, (size_t)kB * sizeof(int), hipMemcpyDeviceToDevice, stream);
    fill_csr<<<dim3((kE + 255) / 256), blk, 0, stream>>>(src_base, dst_base, deg, esort, kE);

    // ---- weight prep
    wT_bf16<<<dim3((256 * 256 + 255) / 256), blk, 0, stream>>>(Wp_c, Wt_c, 256);
    wT_bf16<<<dim3((256 * 512 + 255) / 256), blk, 0, stream>>>(Wp_t, Wt_t, 512);
    wT_bf16<<<dim3((256 * 128 + 255) / 256), blk, 0, stream>>>(Wp_d, Wt_d, 128);
    wT_bf16<<<dim3((256 * 256 + 255) / 256), blk, 0, stream>>>(Wo, Wt_o, 256);
    for (int l = 0; l < 2; ++l)
        wstack2_bf16<<<dim3(5 * 8 * 256 * 32 / 256), blk, 0, stream>>>(
            rgcn_w + (size_t)l * kR * kH * kH, rgcn_root + (size_t)l * kH * kH,
            W2 + (size_t)l * 5 * 8 * 256 * 32);

    // ---- projections (direct f32 A input) -> hA (bf16)
    gemm_mfma_f32a<<<dim3(2, pNC / 128), blk, 0, stream>>>(
        x_c, 256, Wt_c, 256, bp_c, hA, kNC, 256);
    gemm_mfma_f32a<<<dim3(2, pNT / 128), blk, 0, stream>>>(
        x_t, 512, Wt_t, 512, bp_t, hA + (size_t)kNC * kH, kNT, 512);
    gemm_mfma_f32a<<<dim3(2, pND / 128), blk, 0, stream>>>(
        x_d, 128, Wt_d, 128, bp_d, hA + (size_t)(kNC + kNT) * kH, kND, 128);

    // ---- fused RGCN layers (h double-buffered: hA -> hB -> hA)
    const dim3 fusedGrid(kN / 32);     // 3125
    rgcn_fused<<<fusedGrid, blk, 0, stream>>>(
        hA, off, esort, W2, rgcn_b, ln_g, ln_b, hB, 0);
    rgcn_fused<<<fusedGrid, blk, 0, stream>>>(
        hB, off, esort, W2 + (size_t)5 * 8 * 256 * 32,
        rgcn_b + kH, ln_g + kH, ln_b + kH, hA, 1);

    // ---- final: y = h @ Wo + bo -> d_out (f32)
    gemm_mfma<<<dim3(2, pN / 128), blk, 0, stream>>>(
        hA, 256, Wt_o, 256, bo, outf, nullptr, kN, 256, 0);
}